// Round 1
// baseline (1527.416 us; speedup 1.0000x reference)
//
#include <hip/hip_runtime.h>
#include <cstdio>

#define M_DIM 32768   // B*S = 4*8192
#define H_DIM 1024
#define I_DIM 4096

typedef __bf16 bf16x8 __attribute__((ext_vector_type(8)));
typedef float  f32x4  __attribute__((ext_vector_type(4)));

__device__ __forceinline__ unsigned short f2bf(float f) {
    unsigned int u = __float_as_uint(f);
    u += 0x7FFFu + ((u >> 16) & 1u);   // RNE
    return (unsigned short)(u >> 16);
}

__device__ __forceinline__ void async_cp16(const unsigned short* g, unsigned short* l) {
    __builtin_amdgcn_global_load_lds(
        (const __attribute__((address_space(1))) void*)g,
        (__attribute__((address_space(3))) void*)l, 16, 0, 0);
}

// src [R][C] f32 -> dst [C][R] bf16
__global__ __launch_bounds__(256) void transpose_cast_bf16(
    const float* __restrict__ src, unsigned short* __restrict__ dst, int R, int C)
{
    __shared__ float tile[32][33];
    int c0 = blockIdx.x * 32;
    int r0 = blockIdx.y * 32;
    int tx = threadIdx.x;   // 0..31
    int ty = threadIdx.y;   // 0..7
#pragma unroll
    for (int i = 0; i < 32; i += 8)
        tile[ty + i][tx] = src[(size_t)(r0 + ty + i) * C + (c0 + tx)];
    __syncthreads();
#pragma unroll
    for (int i = 0; i < 32; i += 8)
        dst[(size_t)(c0 + ty + i) * R + (r0 + tx)] = f2bf(tile[tx][ty + i]);
}

// residual_add = input + bias + residual ; x = LN(residual_add)*gamma+beta -> bf16
__global__ __launch_bounds__(256) void fused_addln(
    const float* __restrict__ inp, const float* __restrict__ resid,
    const float* __restrict__ bias, const float* __restrict__ gamma,
    const float* __restrict__ beta, unsigned short* __restrict__ xout)
{
    const int row = blockIdx.x;
    const int t = threadIdx.x;                       // 256 threads, H=1024 -> 1 float4 each
    const float4 v = ((const float4*)(inp   + (size_t)row * H_DIM))[t];
    const float4 r = ((const float4*)(resid + (size_t)row * H_DIM))[t];
    const float4 b = ((const float4*)bias)[t];
    float4 x;
    x.x = v.x + b.x + r.x;  x.y = v.y + b.y + r.y;
    x.z = v.z + b.z + r.z;  x.w = v.w + b.w + r.w;
    float s  = x.x + x.y + x.z + x.w;
    float s2 = x.x*x.x + x.y*x.y + x.z*x.z + x.w*x.w;
#pragma unroll
    for (int off = 32; off > 0; off >>= 1) {
        s  += __shfl_down(s,  off, 64);
        s2 += __shfl_down(s2, off, 64);
    }
    __shared__ float red[8];
    const int wid = t >> 6, lane = t & 63;
    if (lane == 0) { red[wid] = s; red[4 + wid] = s2; }
    __syncthreads();
    s  = red[0] + red[1] + red[2] + red[3];
    s2 = red[4] + red[5] + red[6] + red[7];
    const float mu   = s * (1.0f / H_DIM);
    const float var  = s2 * (1.0f / H_DIM) - mu * mu;
    const float rstd = rsqrtf(var + 1e-5f);
    const float4 g  = ((const float4*)gamma)[t];
    const float4 be = ((const float4*)beta)[t];
    ushort4 o;
    o.x = f2bf((x.x - mu) * rstd * g.x + be.x);
    o.y = f2bf((x.y - mu) * rstd * g.y + be.y);
    o.z = f2bf((x.z - mu) * rstd * g.z + be.z);
    o.w = f2bf((x.w - mu) * rstd * g.w + be.w);
    ((ushort4*)(xout + (size_t)row * H_DIM))[t] = o;
}

// C[M][N] = A[M][K] * BT[N][K]^T, m97 structure: 128x128 tile, 4 waves 2x2,
// 4x4 accs of v_mfma_f32_16x16x32_bf16, BK=32, global_load_lds width=16.
// EPI==0: += nbias, tanh-GELU, store bf16.  EPI==1: += nbias + inp + resid + hbias, store f32.
template <int EPI>
__global__ __launch_bounds__(256) void gemm_bt(
    const unsigned short* __restrict__ A,
    const unsigned short* __restrict__ BT,
    unsigned short* __restrict__ outb,
    float* __restrict__ outf,
    const float* __restrict__ nbias,
    const float* __restrict__ inp,
    const float* __restrict__ resid,
    const float* __restrict__ hbias,
    int M, int N, int K)
{
    __shared__ unsigned short As[128 * 32];
    __shared__ unsigned short Bs[128 * 32];

    const int tid  = threadIdx.x;
    const int lane = tid & 63;
    const int wid  = tid >> 6;
    const int wm   = wid & 1;           // wave 2x2 grid over 128x128 tile
    const int wn   = wid >> 1;
    const int m0   = blockIdx.x * 128;
    const int n0   = blockIdx.y * 128;

    // staging: each wave fills rows [wid*32, wid*32+32) of both tiles,
    // 2 x global_load_lds_dwordx4 per tile (16 rows x 32 bf16 per issue)
    const int sr = lane >> 2;           // 0..15
    const int sc = (lane & 3) * 8;      // 0,8,16,24
    const unsigned short* Ag = A  + (size_t)(m0 + wid * 32 + sr) * K + sc;
    const unsigned short* Bg = BT + (size_t)(n0 + wid * 32 + sr) * K + sc;
    unsigned short* Al = &As[(wid * 32) * 32];     // wave-uniform LDS base
    unsigned short* Bl = &Bs[(wid * 32) * 32];
    const size_t rstep = (size_t)16 * K;

    f32x4 acc[4][4] = {};

    const int fr = lane & 15;           // fragment row/col within 16
    const int fq = lane >> 4;           // k-quad
    const int aoff0 = (wm * 64 + fr) * 32 + fq * 8;
    const int boff0 = (wn * 64 + fr) * 32 + fq * 8;

    for (int k0 = 0; k0 < K; k0 += 32) {
        __syncthreads();
        async_cp16(Ag + k0,         Al);
        async_cp16(Ag + k0 + rstep, Al + 16 * 32);
        async_cp16(Bg + k0,         Bl);
        async_cp16(Bg + k0 + rstep, Bl + 16 * 32);
        __syncthreads();   // compiler emits vmcnt(0) drain before s_barrier

        bf16x8 af[4], bfv[4];
#pragma unroll
        for (int mi = 0; mi < 4; mi++)
            af[mi] = *(const bf16x8*)&As[aoff0 + mi * 16 * 32];
#pragma unroll
        for (int ni = 0; ni < 4; ni++)
            bfv[ni] = *(const bf16x8*)&Bs[boff0 + ni * 16 * 32];
#pragma unroll
        for (int mi = 0; mi < 4; mi++)
#pragma unroll
            for (int ni = 0; ni < 4; ni++)
                acc[mi][ni] = __builtin_amdgcn_mfma_f32_16x16x32_bf16(
                    af[mi], bfv[ni], acc[mi][ni], 0, 0, 0);
    }

    // epilogue: C/D layout col=lane&15, row=(lane>>4)*4+reg  [m89-verified]
    const int colb = n0 + wn * 64;
    const int rowb = m0 + wm * 64;
#pragma unroll
    for (int ni = 0; ni < 4; ni++) {
        const int col = colb + ni * 16 + fr;
        const float bn = nbias[col];
#pragma unroll
        for (int mi = 0; mi < 4; mi++) {
            const int row0 = rowb + mi * 16 + fq * 4;
#pragma unroll
            for (int rg = 0; rg < 4; rg++) {
                const size_t idx = (size_t)(row0 + rg) * N + col;
                float v = acc[mi][ni][rg] + bn;
                if (EPI == 0) {
                    // jax.nn.gelu approximate=True
                    float u  = 0.7978845608028654f * (v + 0.044715f * v * v * v);
                    float e  = __expf(2.0f * u);
                    float th = 1.0f - 2.0f / (e + 1.0f);
                    outb[idx] = f2bf(0.5f * v * (1.0f + th));
                } else {
                    outf[idx] = v + inp[idx] + resid[idx] + hbias[col];
                }
            }
        }
    }
}

extern "C" void kernel_launch(void* const* d_in, const int* in_sizes, int n_in,
                              void* d_out, int out_size, void* d_ws, size_t ws_size,
                              hipStream_t stream) {
    const float* input    = (const float*)d_in[0];
    const float* residual = (const float*)d_in[1];
    // d_in[2] residual_norm: unused by the reference
    const float* bias     = (const float*)d_in[3];
    const float* attn_nw  = (const float*)d_in[4];
    const float* attn_nb  = (const float*)d_in[5];
    const float* inter_w  = (const float*)d_in[6];   // [H][I]
    const float* inter_b  = (const float*)d_in[7];   // [I]
    const float* output_w = (const float*)d_in[8];   // [I][H]
    const float* output_b = (const float*)d_in[9];   // [H]
    float* out = (float*)d_out;

    char* ws = (char*)d_ws;
    unsigned short* Xb  = (unsigned short*)ws;                                   // M*H bf16
    unsigned short* W1T = (unsigned short*)(ws + (size_t)M_DIM * H_DIM * 2);     // [I][H]
    unsigned short* W2T = W1T + (size_t)I_DIM * H_DIM;                           // [H][I]
    unsigned short* Hb  = W2T + (size_t)H_DIM * I_DIM;                           // M*I bf16
    const size_t need = (size_t)M_DIM * H_DIM * 2 + 2 * (size_t)I_DIM * H_DIM * 2
                      + (size_t)M_DIM * I_DIM * 2;
    if (ws_size < need)
        fprintf(stderr, "WARNING: ws_size %zu < needed %zu\n", ws_size, need);

    // W1 [H][I] -> W1T [I][H];  W2 [I][H] -> W2T [H][I]
    transpose_cast_bf16<<<dim3(I_DIM / 32, H_DIM / 32), dim3(32, 8), 0, stream>>>(
        inter_w, W1T, H_DIM, I_DIM);
    transpose_cast_bf16<<<dim3(H_DIM / 32, I_DIM / 32), dim3(32, 8), 0, stream>>>(
        output_w, W2T, I_DIM, H_DIM);

    fused_addln<<<M_DIM, 256, 0, stream>>>(input, residual, bias, attn_nw, attn_nb, Xb);

    gemm_bt<0><<<dim3(M_DIM / 128, I_DIM / 128), 256, 0, stream>>>(
        Xb, W1T, Hb, nullptr, inter_b, nullptr, nullptr, nullptr, M_DIM, I_DIM, H_DIM);

    gemm_bt<1><<<dim3(M_DIM / 128, H_DIM / 128), 256, 0, stream>>>(
        Hb, W2T, nullptr, out, output_b, input, residual, bias, M_DIM, H_DIM, I_DIM);
}

// Round 2
// 1374.663 us; speedup vs baseline: 1.1111x; 1.1111x over previous
//
#include <hip/hip_runtime.h>
#include <cstdio>

#define M_DIM 32768   // B*S = 4*8192
#define H_DIM 1024
#define I_DIM 4096

typedef __bf16 bf16x8 __attribute__((ext_vector_type(8)));
typedef float  f32x4  __attribute__((ext_vector_type(4)));

__device__ __forceinline__ unsigned short f2bf(float f) {
    unsigned int u = __float_as_uint(f);
    u += 0x7FFFu + ((u >> 16) & 1u);   // RNE
    return (unsigned short)(u >> 16);
}

__device__ __forceinline__ void async_cp16(const unsigned short* g, unsigned short* l) {
    __builtin_amdgcn_global_load_lds(
        (const __attribute__((address_space(1))) void*)g,
        (__attribute__((address_space(3))) void*)l, 16, 0, 0);
}

// src [R][C] f32 -> dst [C][R] bf16
__global__ __launch_bounds__(256) void transpose_cast_bf16(
    const float* __restrict__ src, unsigned short* __restrict__ dst, int R, int C)
{
    __shared__ float tile[32][33];
    int c0 = blockIdx.x * 32;
    int r0 = blockIdx.y * 32;
    int tx = threadIdx.x;   // 0..31
    int ty = threadIdx.y;   // 0..7
#pragma unroll
    for (int i = 0; i < 32; i += 8)
        tile[ty + i][tx] = src[(size_t)(r0 + ty + i) * C + (c0 + tx)];
    __syncthreads();
#pragma unroll
    for (int i = 0; i < 32; i += 8)
        dst[(size_t)(c0 + ty + i) * R + (r0 + tx)] = f2bf(tile[tx][ty + i]);
}

// residual_add = input + bias + residual ; x = LN(residual_add)*gamma+beta -> bf16
__global__ __launch_bounds__(256) void fused_addln(
    const float* __restrict__ inp, const float* __restrict__ resid,
    const float* __restrict__ bias, const float* __restrict__ gamma,
    const float* __restrict__ beta, unsigned short* __restrict__ xout)
{
    const int row = blockIdx.x;
    const int t = threadIdx.x;                       // 256 threads, H=1024 -> 1 float4 each
    const float4 v = ((const float4*)(inp   + (size_t)row * H_DIM))[t];
    const float4 r = ((const float4*)(resid + (size_t)row * H_DIM))[t];
    const float4 b = ((const float4*)bias)[t];
    float4 x;
    x.x = v.x + b.x + r.x;  x.y = v.y + b.y + r.y;
    x.z = v.z + b.z + r.z;  x.w = v.w + b.w + r.w;
    float s  = x.x + x.y + x.z + x.w;
    float s2 = x.x*x.x + x.y*x.y + x.z*x.z + x.w*x.w;
#pragma unroll
    for (int off = 32; off > 0; off >>= 1) {
        s  += __shfl_down(s,  off, 64);
        s2 += __shfl_down(s2, off, 64);
    }
    __shared__ float red[8];
    const int wid = t >> 6, lane = t & 63;
    if (lane == 0) { red[wid] = s; red[4 + wid] = s2; }
    __syncthreads();
    s  = red[0] + red[1] + red[2] + red[3];
    s2 = red[4] + red[5] + red[6] + red[7];
    const float mu   = s * (1.0f / H_DIM);
    const float var  = s2 * (1.0f / H_DIM) - mu * mu;
    const float rstd = rsqrtf(var + 1e-5f);
    const float4 g  = ((const float4*)gamma)[t];
    const float4 be = ((const float4*)beta)[t];
    ushort4 o;
    o.x = f2bf((x.x - mu) * rstd * g.x + be.x);
    o.y = f2bf((x.y - mu) * rstd * g.y + be.y);
    o.z = f2bf((x.z - mu) * rstd * g.z + be.z);
    o.w = f2bf((x.w - mu) * rstd * g.w + be.w);
    ((ushort4*)(xout + (size_t)row * H_DIM))[t] = o;
}

// C[M][N] = A[M][K] * BT[N][K]^T, m97 structure: 128x128 tile, 4 waves 2x2,
// 4x4 accs of v_mfma_f32_16x16x32_bf16, BK=32, global_load_lds width=16.
// 1D grid with XCD-contiguous + 8-m-tile-strip swizzle for L2/L3 locality.
// EPI==0: += nbias, tanh-GELU, store bf16.  EPI==1: += nbias + inp + resid + hbias, store f32.
template <int EPI>
__global__ __launch_bounds__(256) void gemm_bt(
    const unsigned short* __restrict__ A,
    const unsigned short* __restrict__ BT,
    unsigned short* __restrict__ outb,
    float* __restrict__ outf,
    const float* __restrict__ nbias,
    const float* __restrict__ inp,
    const float* __restrict__ resid,
    const float* __restrict__ hbias,
    int M, int N, int K)
{
    __shared__ unsigned short As[128 * 32];
    __shared__ unsigned short Bs[128 * 32];

    const int tid  = threadIdx.x;
    const int lane = tid & 63;
    const int wid  = tid >> 6;
    const int wm   = wid & 1;           // wave 2x2 grid over 128x128 tile
    const int wn   = wid >> 1;

    // ---- block swizzle ----------------------------------------------------
    // Step 1: invert the round-robin workgroup->XCD dispatch so each XCD
    //         works a contiguous range of logical block ids (L2 locality).
    // Step 2: strip mapping: 8 m-tiles per strip, m fastest, n second ->
    //         ~concurrent blocks share 8 A-tiles + a handful of B-tiles.
    const int mt = M >> 7, nt = N >> 7;
    const int nblk = mt * nt;
    int lbid = blockIdx.x;
    if ((nblk & 7) == 0) {
        const int per = nblk >> 3;
        lbid = (lbid & 7) * per + (lbid >> 3);
    }
    const int strip_blocks = nt << 3;          // 8 m-tiles x nt n-tiles
    const int strip = lbid / strip_blocks;
    const int rem   = lbid - strip * strip_blocks;
    const int m0 = (strip * 8 + (rem & 7)) << 7;
    const int n0 = (rem >> 3) << 7;
    // -----------------------------------------------------------------------

    // staging: each wave fills rows [wid*32, wid*32+32) of both tiles,
    // 2 x global_load_lds_dwordx4 per tile (16 rows x 32 bf16 per issue)
    const int sr = lane >> 2;           // 0..15
    const int sc = (lane & 3) * 8;      // 0,8,16,24
    const unsigned short* Ag = A  + (size_t)(m0 + wid * 32 + sr) * K + sc;
    const unsigned short* Bg = BT + (size_t)(n0 + wid * 32 + sr) * K + sc;
    unsigned short* Al = &As[(wid * 32) * 32];     // wave-uniform LDS base
    unsigned short* Bl = &Bs[(wid * 32) * 32];
    const size_t rstep = (size_t)16 * K;

    f32x4 acc[4][4] = {};

    const int fr = lane & 15;           // fragment row/col within 16
    const int fq = lane >> 4;           // k-quad
    const int aoff0 = (wm * 64 + fr) * 32 + fq * 8;
    const int boff0 = (wn * 64 + fr) * 32 + fq * 8;

    for (int k0 = 0; k0 < K; k0 += 32) {
        __syncthreads();
        async_cp16(Ag + k0,         Al);
        async_cp16(Ag + k0 + rstep, Al + 16 * 32);
        async_cp16(Bg + k0,         Bl);
        async_cp16(Bg + k0 + rstep, Bl + 16 * 32);
        __syncthreads();   // compiler emits vmcnt(0) drain before s_barrier

        bf16x8 af[4], bfv[4];
#pragma unroll
        for (int mi = 0; mi < 4; mi++)
            af[mi] = *(const bf16x8*)&As[aoff0 + mi * 16 * 32];
#pragma unroll
        for (int ni = 0; ni < 4; ni++)
            bfv[ni] = *(const bf16x8*)&Bs[boff0 + ni * 16 * 32];
#pragma unroll
        for (int mi = 0; mi < 4; mi++)
#pragma unroll
            for (int ni = 0; ni < 4; ni++)
                acc[mi][ni] = __builtin_amdgcn_mfma_f32_16x16x32_bf16(
                    af[mi], bfv[ni], acc[mi][ni], 0, 0, 0);
    }

    // epilogue: C/D layout col=lane&15, row=(lane>>4)*4+reg  [m89-verified]
    const int colb = n0 + wn * 64;
    const int rowb = m0 + wm * 64;
#pragma unroll
    for (int ni = 0; ni < 4; ni++) {
        const int col = colb + ni * 16 + fr;
        const float bn = nbias[col];
#pragma unroll
        for (int mi = 0; mi < 4; mi++) {
            const int row0 = rowb + mi * 16 + fq * 4;
#pragma unroll
            for (int rg = 0; rg < 4; rg++) {
                const size_t idx = (size_t)(row0 + rg) * N + col;
                float v = acc[mi][ni][rg] + bn;
                if (EPI == 0) {
                    // jax.nn.gelu approximate=True
                    float u  = 0.7978845608028654f * (v + 0.044715f * v * v * v);
                    float e  = __expf(2.0f * u);
                    float th = 1.0f - 2.0f / (e + 1.0f);
                    outb[idx] = f2bf(0.5f * v * (1.0f + th));
                } else {
                    outf[idx] = v + inp[idx] + resid[idx] + hbias[col];
                }
            }
        }
    }
}

extern "C" void kernel_launch(void* const* d_in, const int* in_sizes, int n_in,
                              void* d_out, int out_size, void* d_ws, size_t ws_size,
                              hipStream_t stream) {
    const float* input    = (const float*)d_in[0];
    const float* residual = (const float*)d_in[1];
    // d_in[2] residual_norm: unused by the reference
    const float* bias     = (const float*)d_in[3];
    const float* attn_nw  = (const float*)d_in[4];
    const float* attn_nb  = (const float*)d_in[5];
    const float* inter_w  = (const float*)d_in[6];   // [H][I]
    const float* inter_b  = (const float*)d_in[7];   // [I]
    const float* output_w = (const float*)d_in[8];   // [I][H]
    const float* output_b = (const float*)d_in[9];   // [H]
    float* out = (float*)d_out;

    char* ws = (char*)d_ws;
    unsigned short* Xb  = (unsigned short*)ws;                                   // M*H bf16
    unsigned short* W1T = (unsigned short*)(ws + (size_t)M_DIM * H_DIM * 2);     // [I][H]
    unsigned short* W2T = W1T + (size_t)I_DIM * H_DIM;                           // [H][I]
    unsigned short* Hb  = W2T + (size_t)H_DIM * I_DIM;                           // M*I bf16
    const size_t need = (size_t)M_DIM * H_DIM * 2 + 2 * (size_t)I_DIM * H_DIM * 2
                      + (size_t)M_DIM * I_DIM * 2;
    if (ws_size < need)
        fprintf(stderr, "WARNING: ws_size %zu < needed %zu\n", ws_size, need);

    // W1 [H][I] -> W1T [I][H];  W2 [I][H] -> W2T [H][I]
    transpose_cast_bf16<<<dim3(I_DIM / 32, H_DIM / 32), dim3(32, 8), 0, stream>>>(
        inter_w, W1T, H_DIM, I_DIM);
    transpose_cast_bf16<<<dim3(H_DIM / 32, I_DIM / 32), dim3(32, 8), 0, stream>>>(
        output_w, W2T, I_DIM, H_DIM);

    fused_addln<<<M_DIM, 256, 0, stream>>>(input, residual, bias, attn_nw, attn_nb, Xb);

    gemm_bt<0><<<(M_DIM / 128) * (I_DIM / 128), 256, 0, stream>>>(
        Xb, W1T, Hb, nullptr, inter_b, nullptr, nullptr, nullptr, M_DIM, I_DIM, H_DIM);

    gemm_bt<1><<<(M_DIM / 128) * (H_DIM / 128), 256, 0, stream>>>(
        Hb, W2T, nullptr, out, output_b, input, residual, bias, M_DIM, H_DIM, I_DIM);
}